// Round 5
// baseline (863.629 us; speedup 1.0000x reference)
//
#include <hip/hip_runtime.h>

#define BB 16
#define NN 4096
#define SS 1024
#define KNB 32
#define FPT 16    // points per thread in FPS (4096/256)
#define FNW 4     // waves per 256-thread FPS block

typedef unsigned long long ull;
typedef float v2f __attribute__((ext_vector_type(2)));

// exact f32 squared distance, left-to-right, no fma contraction (matches numpy)
__device__ __forceinline__ float sqd3(float dx, float dy, float dz) {
    return __fadd_rn(__fadd_rn(__fmul_rn(dx, dx), __fmul_rn(dy, dy)), __fmul_rn(dz, dz));
}

// one DPP max step on u32 (float bits of non-negative floats: u32 max == float max)
#define DPPMAX(m, ctrl, rm)                                                              \
    {                                                                                    \
        unsigned _t = (unsigned)__builtin_amdgcn_update_dpp((int)(m), (int)(m), (ctrl),  \
                                                            (rm), 0xf, false);           \
        (m) = ((m) > _t) ? (m) : _t;                                                     \
    }

// ---------------- Kernel 1: fused FPS (blocks 0..15) + P1/xyz4 (blocks 16..271) ----------
__global__ __launch_bounds__(256) void fused1_kernel(const float* __restrict__ xyz,
                                                     const float* __restrict__ points,
                                                     const float* __restrict__ W0,
                                                     const float* __restrict__ b0,
                                                     float* __restrict__ P1,
                                                     float4* __restrict__ xyz4,
                                                     float* __restrict__ out_newxyz) {
    __shared__ union {
        struct {
            float4 pts4[NN];          // 64 KB
            ull    rkey[2][FNW];      // parity double-buffered candidate records
            float  rx[2][FNW];
            float  ry[2][FNW];
            float  rz[2][FNW];
            int    hist[SS];          // selected index per iteration
        } f;
        float w0s[67 * 64];
    } sm;

    const int t = threadIdx.x;

    if (blockIdx.x < BB) {
        // ---------------- FPS: one block per batch, 4 waves, 16 pts/thread ----------------
        const int b = blockIdx.x;
        const int lane = t & 63;
        const int wv = t >> 6;
        const float* src = xyz + (size_t)b * (NN * 3) + (size_t)t * (FPT * 3);

        v2f px2[8], py2[8], pz2[8], d2[8];
        {
            float c48[48];
#pragma unroll
            for (int m = 0; m < 12; ++m) {
                float4 v = ((const float4*)src)[m];
                c48[4 * m + 0] = v.x; c48[4 * m + 1] = v.y;
                c48[4 * m + 2] = v.z; c48[4 * m + 3] = v.w;
            }
#pragma unroll
            for (int j = 0; j < 8; ++j) {
                px2[j] = (v2f){c48[6 * j + 0], c48[6 * j + 3]};
                py2[j] = (v2f){c48[6 * j + 1], c48[6 * j + 4]};
                pz2[j] = (v2f){c48[6 * j + 2], c48[6 * j + 5]};
                d2[j]  = (v2f){1e10f, 1e10f};
                sm.f.pts4[t * FPT + 2 * j + 0] = make_float4(px2[j].x, py2[j].x, pz2[j].x, 0.f);
                sm.f.pts4[t * FPT + 2 * j + 1] = make_float4(px2[j].y, py2[j].y, pz2[j].y, 0.f);
            }
        }
        __syncthreads();

        float4 cv = sm.f.pts4[0];
        float cx = cv.x, cy = cv.y, cz = cv.z;
        int far = 0;
        for (int it = 0; it < SS; ++it) {
            if (t == 0) sm.f.hist[it] = far;
            if (it == SS - 1) break;

            float bv = -1.f;
            int bn = 0;
            {
#pragma clang fp contract(off)
                v2f cx2 = {cx, cx}, cy2 = {cy, cy}, cz2 = {cz, cz};
#pragma unroll
                for (int j = 0; j < 8; ++j) {
                    v2f dx = px2[j] - cx2;
                    v2f dy = py2[j] - cy2;
                    v2f dz = pz2[j] - cz2;
                    v2f s = (dx * dx + dy * dy) + dz * dz;  // pk mul/add, separate rounding
                    float d0 = fminf(d2[j].x, s.x);
                    float d1 = fminf(d2[j].y, s.y);
                    d2[j] = (v2f){d0, d1};
                    bool g0 = d0 > bv;                       // strict > keeps earliest idx
                    bv = g0 ? d0 : bv;
                    bn = g0 ? (t * FPT + 2 * j + 0) : bn;
                    bool g1 = d1 > bv;
                    bv = g1 ? d1 : bv;
                    bn = g1 ? (t * FPT + 2 * j + 1) : bn;
                }
            }

            // wave64 DPP max reduce (value only) -> lane 63
            unsigned mb = __float_as_uint(bv);
            DPPMAX(mb, 0x111, 0xf);  // row_shr:1
            DPPMAX(mb, 0x112, 0xf);  // row_shr:2
            DPPMAX(mb, 0x114, 0xf);  // row_shr:4
            DPPMAX(mb, 0x118, 0xf);  // row_shr:8
            DPPMAX(mb, 0x142, 0xa);  // row_bcast:15 -> rows 1,3
            DPPMAX(mb, 0x143, 0xc);  // row_bcast:31 -> rows 2,3
            unsigned vmb = (unsigned)__builtin_amdgcn_readlane((int)mb, 63);

            // earliest lane achieving the max == smallest index (contiguous ownership)
            ull ball = __ballot(__float_as_uint(bv) == vmb);
            int sel = __ffsll(ball) - 1;
            int bnw = __builtin_amdgcn_readlane(bn, sel);

            // wave candidate coords: uniform-address LDS read, overlaps barrier arrival
            float4 wc = sm.f.pts4[bnw];
            const int par = it & 1;
            if (lane == sel) {
                sm.f.rkey[par][wv] = ((ull)vmb << 32) | (unsigned)(~bnw);
                sm.f.rx[par][wv] = wc.x;
                sm.f.ry[par][wv] = wc.y;
                sm.f.rz[par][wv] = wc.z;
            }
            __syncthreads();

            // combine 4 wave records (u64 key max = value max, min-index tiebreak)
            ull k0 = sm.f.rkey[par][0], k1 = sm.f.rkey[par][1];
            ull k2 = sm.f.rkey[par][2], k3 = sm.f.rkey[par][3];
            float x0 = sm.f.rx[par][0], x1 = sm.f.rx[par][1], x2 = sm.f.rx[par][2], x3 = sm.f.rx[par][3];
            float y0 = sm.f.ry[par][0], y1 = sm.f.ry[par][1], y2 = sm.f.ry[par][2], y3 = sm.f.ry[par][3];
            float z0 = sm.f.rz[par][0], z1 = sm.f.rz[par][1], z2 = sm.f.rz[par][2], z3 = sm.f.rz[par][3];
            bool ga = k1 > k0;
            ull ka = ga ? k1 : k0; float xa = ga ? x1 : x0; float ya = ga ? y1 : y0; float za = ga ? z1 : z0;
            bool gb = k3 > k2;
            ull kb = gb ? k3 : k2; float xb = gb ? x3 : x2; float yb = gb ? y3 : y2; float zb = gb ? z3 : z2;
            bool gc = kb > ka;
            ull kf = gc ? kb : ka;
            cx = gc ? xb : xa; cy = gc ? yb : ya; cz = gc ? zb : za;
            far = (int)(~(unsigned)kf);
        }
        __syncthreads();
        // write new_xyz from history
#pragma unroll
        for (int r = 0; r < 4; ++r) {
            int it2 = t + 256 * r;
            int fi = sm.f.hist[it2];
            float4 c = sm.f.pts4[fi];
            size_t o = ((size_t)b * SS + it2) * 3;
            out_newxyz[o + 0] = c.x;
            out_newxyz[o + 1] = c.y;
            out_newxyz[o + 2] = c.z;
        }
    } else {
        // ---------------- P1 + xyz4 path: 256 points per block ----------------
        for (int i = t; i < 67 * 64; i += 256) sm.w0s[i] = W0[i];
        __syncthreads();
        const int lane = t & 63;
        const int wv = t >> 6;

        // packed xyz for k3's ball query
        {
            int n0 = (blockIdx.x - BB) * 256 + t;
            xyz4[n0] = make_float4(xyz[3 * n0 + 0], xyz[3 * n0 + 1], xyz[3 * n0 + 2], 0.f);
        }

        const float bias = b0[lane];
        const int base = (blockIdx.x - BB) * 256 + wv * 64;
        for (int pi = 0; pi < 64; ++pi) {
            const int n = base + pi;  // 0 .. B*N-1
            const float* xp = xyz + (size_t)n * 3;
            const float* pp = points + (size_t)n * 64;
            float acc = bias;
            acc = fmaf(xp[0], sm.w0s[0 * 64 + lane], acc);
            acc = fmaf(xp[1], sm.w0s[1 * 64 + lane], acc);
            acc = fmaf(xp[2], sm.w0s[2 * 64 + lane], acc);
#pragma unroll 8
            for (int c = 0; c < 64; ++c) acc = fmaf(pp[c], sm.w0s[(3 + c) * 64 + lane], acc);
            P1[(size_t)n * 64 + lane] = acc;
        }
    }
}

// ---------------- Kernel 3: ball query + MLP(l2,l3) + max, one block per (b,s) ----------------
__global__ __launch_bounds__(256) void k3_kernel(const float4* __restrict__ xyz4,
                                                 const float* __restrict__ P1,
                                                 const float* __restrict__ W0,
                                                 const float* __restrict__ W1,
                                                 const float* __restrict__ b1,
                                                 const float* __restrict__ W2,
                                                 const float* __restrict__ b2,
                                                 float* __restrict__ d_out) {
    const int t = threadIdx.x;
    const int lane = t & 63;
    const int wv = t >> 6;
    const int b = blockIdx.x >> 10;

    __shared__ int   ids[KNB];
    __shared__ int   bq[2][FNW];
    __shared__ float part[4][128];
    __shared__ float hs[4][8][64];   // h1, then aliased as h2 (wave-lockstep safe)

    float* out_newxyz = d_out;                                   // B*S*3
    float* out_points = d_out + (size_t)BB * SS * 3;             // B*S*128
    float* out_idx    = d_out + (size_t)BB * SS * 3 + (size_t)BB * SS * 128;  // B*S*32

    const size_t q = (size_t)blockIdx.x;  // b*S + s
    const float nx = out_newxyz[q * 3 + 0];
    const float ny = out_newxyz[q * 3 + 1];
    const float nz = out_newxyz[q * 3 + 2];

    // per-channel query projection (layer1 factorization) + early weight loads
    const float qv = nx * W0[lane] + ny * W0[64 + lane] + nz * W0[128 + lane];
    float w1col[64];
#pragma unroll
    for (int i = 0; i < 64; ++i) w1col[i] = W1[i * 64 + lane];
    const float b1v = b1[lane];

    // ---- ball query: 4 waves scan 4 chunks of 64 per round, prefetched ----
    {
        const float4* xb4 = xyz4 + (size_t)b * NN;
        const float R2 = 0.04f;  // float(0.2*0.2)
        const ull ltm = (1ull << lane) - 1ull;
        int total = 0, c0 = 0, pr = 0;
        float4 pc = xb4[t];
        while (true) {
            float4 cur = pc;
            int nc0 = c0 + 256;
            if (nc0 < NN) pc = xb4[nc0 + t];
            float d = sqd3(cur.x - nx, cur.y - ny, cur.z - nz);
            bool in = (d <= R2);
            ull m = __ballot(in);
            if (lane == 0) bq[pr][wv] = __popcll(m);
            __syncthreads();
            int q0 = bq[pr][0], q1 = bq[pr][1], q2 = bq[pr][2], q3 = bq[pr][3];
            int basew = total + (wv > 0 ? q0 : 0) + (wv > 1 ? q1 : 0) + (wv > 2 ? q2 : 0);
            int pos = basew + __popcll(m & ltm);
            if (in && pos < KNB) ids[pos] = c0 + t;
            total += q0 + q1 + q2 + q3;
            c0 = nc0;
            pr ^= 1;
            if (total >= KNB || c0 >= NN) break;
        }
        __syncthreads();
        int cnt = (total < KNB) ? total : KNB;
        if (t >= cnt && t < KNB) ids[t] = ids[0];  // pad with first (reference semantics)
    }
    __syncthreads();
    if (t < KNB) out_idx[q * KNB + t] = (float)ids[t];

    // ---- gather + layer1: h1[k][i=lane] = relu(P1[n_k][lane] - qv) ----
    const float* P1b = P1 + (size_t)b * NN * 64;
#pragma unroll
    for (int kk = 0; kk < 8; ++kk) {
        int n = ids[wv * 8 + kk];
        float v = P1b[(size_t)n * 64 + lane] - qv;
        hs[wv][kk][lane] = fmaxf(v, 0.f);
    }

    // ---- layer2: acc[k][o=lane] = b1 + sum_i h1[k][i] * W1[i][o] ----
    float acc[8];
#pragma unroll
    for (int kk = 0; kk < 8; ++kk) acc[kk] = b1v;
#pragma unroll
    for (int qd = 0; qd < 16; ++qd) {
#pragma unroll
        for (int kk = 0; kk < 8; ++kk) {
            float4 h4 = *(const float4*)&hs[wv][kk][4 * qd];
            acc[kk] = fmaf(h4.x, w1col[4 * qd + 0], acc[kk]);
            acc[kk] = fmaf(h4.y, w1col[4 * qd + 1], acc[kk]);
            acc[kk] = fmaf(h4.z, w1col[4 * qd + 2], acc[kk]);
            acc[kk] = fmaf(h4.w, w1col[4 * qd + 3], acc[kk]);
        }
    }
    // overwrite h1 with h2 in the same LDS (all reads above precede writes, per-wave private)
#pragma unroll
    for (int kk = 0; kk < 8; ++kk) hs[wv][kk][lane] = fmaxf(acc[kk], 0.f);

    // ---- layer3 (two o-halves) + max over this wave's 8 k ----
    float outmax[2];
#pragma unroll
    for (int p = 0; p < 2; ++p) {
        float w2col[64];
#pragma unroll
        for (int i = 0; i < 64; ++i) w2col[i] = W2[i * 128 + 64 * p + lane];
        const float b2v = b2[64 * p + lane];
        float acc3[8];
#pragma unroll
        for (int kk = 0; kk < 8; ++kk) acc3[kk] = b2v;
#pragma unroll
        for (int qd = 0; qd < 16; ++qd) {
#pragma unroll
            for (int kk = 0; kk < 8; ++kk) {
                float4 h4 = *(const float4*)&hs[wv][kk][4 * qd];
                acc3[kk] = fmaf(h4.x, w2col[4 * qd + 0], acc3[kk]);
                acc3[kk] = fmaf(h4.y, w2col[4 * qd + 1], acc3[kk]);
                acc3[kk] = fmaf(h4.z, w2col[4 * qd + 2], acc3[kk]);
                acc3[kk] = fmaf(h4.w, w2col[4 * qd + 3], acc3[kk]);
            }
        }
        float m = 0.f;  // relu floor: max(relu(x)) == max(0, max(x))
#pragma unroll
        for (int kk = 0; kk < 8; ++kk) m = fmaxf(m, acc3[kk]);
        outmax[p] = m;
    }
    part[wv][lane] = outmax[0];
    part[wv][64 + lane] = outmax[1];
    __syncthreads();
    if (t < 128) {
        float v = fmaxf(fmaxf(part[0][t], part[1][t]), fmaxf(part[2][t], part[3][t]));
        out_points[q * 128 + t] = v;
    }
}

extern "C" void kernel_launch(void* const* d_in, const int* in_sizes, int n_in,
                              void* d_out, int out_size, void* d_ws, size_t ws_size,
                              hipStream_t stream) {
    const float* xyz    = (const float*)d_in[0];
    const float* points = (const float*)d_in[1];
    const float* W0     = (const float*)d_in[2];
    const float* b0     = (const float*)d_in[3];
    const float* W1     = (const float*)d_in[4];
    const float* b1     = (const float*)d_in[5];
    const float* W2     = (const float*)d_in[6];
    const float* b2     = (const float*)d_in[7];
    float* out = (float*)d_out;
    float*  P1   = (float*)d_ws;                                        // B*N*64 f32 = 16 MB
    float4* xyz4 = (float4*)((char*)d_ws + (size_t)BB * NN * 64 * 4);   // B*N float4 = 1 MB

    // blocks 0..15: FPS (one per batch); blocks 16..271: P1+xyz4 (256 points each)
    hipLaunchKernelGGL(fused1_kernel, dim3(BB + (BB * NN) / 256), dim3(256), 0, stream,
                       xyz, points, W0, b0, P1, xyz4, out);
    hipLaunchKernelGGL(k3_kernel, dim3(BB * SS), dim3(256), 0, stream,
                       xyz4, P1, W0, W1, b1, W2, b2, out);
}

// Round 6
// 748.931 us; speedup vs baseline: 1.1531x; 1.1531x over previous
//
#include <hip/hip_runtime.h>

#define BB 16
#define NN 4096
#define SS 1024
#define KNB 32
#define FPT 16    // points per thread in FPS (4096/256)
#define FNW 4     // waves per 256-thread FPS block

typedef unsigned long long ull;
typedef float v2f __attribute__((ext_vector_type(2)));

// exact f32 squared distance, left-to-right, no fma contraction (matches numpy)
__device__ __forceinline__ float sqd3(float dx, float dy, float dz) {
    return __fadd_rn(__fadd_rn(__fmul_rn(dx, dx), __fmul_rn(dy, dy)), __fmul_rn(dz, dz));
}

// one DPP max step on u32 (float bits of non-negative floats: u32 max == float max)
#define DPPMAX(m, ctrl, rm)                                                              \
    {                                                                                    \
        unsigned _t = (unsigned)__builtin_amdgcn_update_dpp((int)(m), (int)(m), (ctrl),  \
                                                            (rm), 0xf, false);           \
        (m) = ((m) > _t) ? (m) : _t;                                                     \
    }

// ---------------- Kernel 1: fused FPS (blocks 0..15) + P1/xyz4 (blocks 16..271) ----------
__global__ __launch_bounds__(256) void fused1_kernel(const float* __restrict__ xyz,
                                                     const float* __restrict__ points,
                                                     const float* __restrict__ W0,
                                                     const float* __restrict__ b0,
                                                     float* __restrict__ P1,
                                                     float4* __restrict__ xyz4,
                                                     float* __restrict__ out_newxyz) {
    __shared__ union {
        struct {
            float4 pts4[NN];          // 64 KB, 16B-aligned
            ull    keys[2][FNW];      // parity double-buffered wave keys (16B-aligned)
            int    hist[SS];          // selected index per iteration
        } f;
        float w0s[67 * 64];
    } sm;

    const int t = threadIdx.x;

    if (blockIdx.x < BB) {
        // ---------------- FPS: one block per batch, 4 waves, 16 pts/thread ----------------
        const int b = blockIdx.x;
        const int lane = t & 63;
        const float* src = xyz + (size_t)b * (NN * 3) + (size_t)t * (FPT * 3);

        v2f px2[8], py2[8], pz2[8], d2[8];
        {
            float c48[48];
#pragma unroll
            for (int m = 0; m < 12; ++m) {
                float4 v = ((const float4*)src)[m];
                c48[4 * m + 0] = v.x; c48[4 * m + 1] = v.y;
                c48[4 * m + 2] = v.z; c48[4 * m + 3] = v.w;
            }
#pragma unroll
            for (int j = 0; j < 8; ++j) {
                px2[j] = (v2f){c48[6 * j + 0], c48[6 * j + 3]};
                py2[j] = (v2f){c48[6 * j + 1], c48[6 * j + 4]};
                pz2[j] = (v2f){c48[6 * j + 2], c48[6 * j + 5]};
                d2[j]  = (v2f){1e10f, 1e10f};
                sm.f.pts4[t * FPT + 2 * j + 0] = make_float4(px2[j].x, py2[j].x, pz2[j].x, 0.f);
                sm.f.pts4[t * FPT + 2 * j + 1] = make_float4(px2[j].y, py2[j].y, pz2[j].y, 0.f);
            }
        }
        __syncthreads();

        int far = 0;
        for (int it = 0; it < SS; ++it) {
            if (t == 0) sm.f.hist[it] = far;
            if (it == SS - 1) break;
            float4 c = sm.f.pts4[far];   // uniform-address b128 read

            // update min-dists (packed) + two-half argmax chains (exact first-index ties)
            float bv0 = -1.f, bv1 = -1.f;
            int bn0 = 0, bn1 = 0;
            {
#pragma clang fp contract(off)
                v2f cx2 = {c.x, c.x}, cy2 = {c.y, c.y}, cz2 = {c.z, c.z};
#pragma unroll
                for (int j = 0; j < 4; ++j) {      // slots 0..7
                    v2f dx = px2[j] - cx2;
                    v2f dy = py2[j] - cy2;
                    v2f dz = pz2[j] - cz2;
                    v2f s = (dx * dx + dy * dy) + dz * dz;
                    float d0 = fminf(d2[j].x, s.x);
                    float d1 = fminf(d2[j].y, s.y);
                    d2[j] = (v2f){d0, d1};
                    bool g0 = d0 > bv0; bv0 = g0 ? d0 : bv0; bn0 = g0 ? (t * FPT + 2 * j + 0) : bn0;
                    bool g1 = d1 > bv0; bv0 = g1 ? d1 : bv0; bn0 = g1 ? (t * FPT + 2 * j + 1) : bn0;
                }
#pragma unroll
                for (int j = 4; j < 8; ++j) {      // slots 8..15
                    v2f dx = px2[j] - cx2;
                    v2f dy = py2[j] - cy2;
                    v2f dz = pz2[j] - cz2;
                    v2f s = (dx * dx + dy * dy) + dz * dz;
                    float d0 = fminf(d2[j].x, s.x);
                    float d1 = fminf(d2[j].y, s.y);
                    d2[j] = (v2f){d0, d1};
                    bool g0 = d0 > bv1; bv1 = g0 ? d0 : bv1; bn1 = g0 ? (t * FPT + 2 * j + 0) : bn1;
                    bool g1 = d1 > bv1; bv1 = g1 ? d1 : bv1; bn1 = g1 ? (t * FPT + 2 * j + 1) : bn1;
                }
            }
            // merge halves: strict > keeps lower-index half on ties
            bool gm = bv1 > bv0;
            float bv = gm ? bv1 : bv0;
            int bn = gm ? bn1 : bn0;

            // wave64 DPP max reduce (value only)
            unsigned mb = __float_as_uint(bv);
            DPPMAX(mb, 0x111, 0xf);  // row_shr:1
            DPPMAX(mb, 0x112, 0xf);  // row_shr:2
            DPPMAX(mb, 0x114, 0xf);  // row_shr:4
            DPPMAX(mb, 0x118, 0xf);  // row_shr:8
            DPPMAX(mb, 0x142, 0xa);  // row_bcast:15 -> rows 1,3
            DPPMAX(mb, 0x143, 0xc);  // row_bcast:31 -> rows 2,3
            unsigned vmb = (unsigned)__builtin_amdgcn_readlane((int)mb, 63);

            // earliest lane achieving the max == smallest index (contiguous ownership)
            ull ball = __ballot(__float_as_uint(bv) == vmb);
            int sel = __ffsll(ball) - 1;
            int widx = __builtin_amdgcn_readlane(bn, sel);

            const int par = it & 1;
            if (lane == 0) {
                sm.f.keys[par][t >> 6] = ((ull)vmb << 32) | (unsigned)(~widx);
            }
            __syncthreads();
            // combine 4 wave keys (2 x b128 read; u64 max = value max, min-index tiebreak)
            ulonglong2 ka = *(const ulonglong2*)&sm.f.keys[par][0];
            ulonglong2 kb = *(const ulonglong2*)&sm.f.keys[par][2];
            ull a0 = (ka.x > ka.y) ? ka.x : ka.y;
            ull a1 = (kb.x > kb.y) ? kb.x : kb.y;
            ull best = (a0 > a1) ? a0 : a1;
            far = (int)(~(unsigned)best);
        }
        __syncthreads();
        // write new_xyz from history
#pragma unroll
        for (int r = 0; r < 4; ++r) {
            int it2 = t + 256 * r;
            int fi = sm.f.hist[it2];
            float4 c = sm.f.pts4[fi];
            size_t o = ((size_t)b * SS + it2) * 3;
            out_newxyz[o + 0] = c.x;
            out_newxyz[o + 1] = c.y;
            out_newxyz[o + 2] = c.z;
        }
    } else {
        // ---------------- P1 + xyz4 path: 256 points per block ----------------
        for (int i = t; i < 67 * 64; i += 256) sm.w0s[i] = W0[i];
        __syncthreads();
        const int lane = t & 63;
        const int wv = t >> 6;

        // packed xyz for k3's ball query
        {
            int n0 = (blockIdx.x - BB) * 256 + t;
            xyz4[n0] = make_float4(xyz[3 * n0 + 0], xyz[3 * n0 + 1], xyz[3 * n0 + 2], 0.f);
        }

        const float bias = b0[lane];
        const int base = (blockIdx.x - BB) * 256 + wv * 64;
        for (int pi = 0; pi < 64; ++pi) {
            const int n = base + pi;  // 0 .. B*N-1
            const float* xp = xyz + (size_t)n * 3;
            const float* pp = points + (size_t)n * 64;
            float acc = bias;
            acc = fmaf(xp[0], sm.w0s[0 * 64 + lane], acc);
            acc = fmaf(xp[1], sm.w0s[1 * 64 + lane], acc);
            acc = fmaf(xp[2], sm.w0s[2 * 64 + lane], acc);
#pragma unroll 8
            for (int c = 0; c < 64; ++c) acc = fmaf(pp[c], sm.w0s[(3 + c) * 64 + lane], acc);
            P1[(size_t)n * 64 + lane] = acc;
        }
    }
}

// ---------------- Kernel 3: ball query + MLP(l2,l3) + max, one block per (b,s) ----------------
__global__ __launch_bounds__(256) void k3_kernel(const float4* __restrict__ xyz4,
                                                 const float* __restrict__ P1,
                                                 const float* __restrict__ W0,
                                                 const float* __restrict__ W1,
                                                 const float* __restrict__ b1,
                                                 const float* __restrict__ W2,
                                                 const float* __restrict__ b2,
                                                 float* __restrict__ d_out) {
    const int t = threadIdx.x;
    const int lane = t & 63;
    const int wv = t >> 6;
    const int b = blockIdx.x >> 10;

    __shared__ int   ids[KNB];
    __shared__ int   bq[2][FNW];
    __shared__ float part[4][128];
    __shared__ float hs[4][8][64];   // h1, then aliased as h2 (wave-lockstep safe)

    float* out_newxyz = d_out;                                   // B*S*3
    float* out_points = d_out + (size_t)BB * SS * 3;             // B*S*128
    float* out_idx    = d_out + (size_t)BB * SS * 3 + (size_t)BB * SS * 128;  // B*S*32

    const size_t q = (size_t)blockIdx.x;  // b*S + s
    const float nx = out_newxyz[q * 3 + 0];
    const float ny = out_newxyz[q * 3 + 1];
    const float nz = out_newxyz[q * 3 + 2];

    // per-channel query projection (layer1 factorization) + early weight loads
    const float qv = nx * W0[lane] + ny * W0[64 + lane] + nz * W0[128 + lane];
    float w1col[64];
#pragma unroll
    for (int i = 0; i < 64; ++i) w1col[i] = W1[i * 64 + lane];
    const float b1v = b1[lane];

    // ---- ball query: 4 waves scan 4 chunks of 64 per round, prefetched ----
    {
        const float4* xb4 = xyz4 + (size_t)b * NN;
        const float R2 = 0.04f;  // float(0.2*0.2)
        const ull ltm = (1ull << lane) - 1ull;
        int total = 0, c0 = 0, pr = 0;
        float4 pc = xb4[t];
        while (true) {
            float4 cur = pc;
            int nc0 = c0 + 256;
            if (nc0 < NN) pc = xb4[nc0 + t];
            float d = sqd3(cur.x - nx, cur.y - ny, cur.z - nz);
            bool in = (d <= R2);
            ull m = __ballot(in);
            if (lane == 0) bq[pr][wv] = __popcll(m);
            __syncthreads();
            int q0 = bq[pr][0], q1 = bq[pr][1], q2 = bq[pr][2], q3 = bq[pr][3];
            int basew = total + (wv > 0 ? q0 : 0) + (wv > 1 ? q1 : 0) + (wv > 2 ? q2 : 0);
            int pos = basew + __popcll(m & ltm);
            if (in && pos < KNB) ids[pos] = c0 + t;
            total += q0 + q1 + q2 + q3;
            c0 = nc0;
            pr ^= 1;
            if (total >= KNB || c0 >= NN) break;
        }
        __syncthreads();
        int cnt = (total < KNB) ? total : KNB;
        if (t >= cnt && t < KNB) ids[t] = ids[0];  // pad with first (reference semantics)
    }
    __syncthreads();
    if (t < KNB) out_idx[q * KNB + t] = (float)ids[t];

    // ---- gather + layer1: h1[k][i=lane] = relu(P1[n_k][lane] - qv) ----
    const float* P1b = P1 + (size_t)b * NN * 64;
#pragma unroll
    for (int kk = 0; kk < 8; ++kk) {
        int n = ids[wv * 8 + kk];
        float v = P1b[(size_t)n * 64 + lane] - qv;
        hs[wv][kk][lane] = fmaxf(v, 0.f);
    }

    // ---- layer2: acc[k][o=lane] = b1 + sum_i h1[k][i] * W1[i][o] ----
    float acc[8];
#pragma unroll
    for (int kk = 0; kk < 8; ++kk) acc[kk] = b1v;
#pragma unroll
    for (int qd = 0; qd < 16; ++qd) {
#pragma unroll
        for (int kk = 0; kk < 8; ++kk) {
            float4 h4 = *(const float4*)&hs[wv][kk][4 * qd];
            acc[kk] = fmaf(h4.x, w1col[4 * qd + 0], acc[kk]);
            acc[kk] = fmaf(h4.y, w1col[4 * qd + 1], acc[kk]);
            acc[kk] = fmaf(h4.z, w1col[4 * qd + 2], acc[kk]);
            acc[kk] = fmaf(h4.w, w1col[4 * qd + 3], acc[kk]);
        }
    }
    // overwrite h1 with h2 in the same LDS (all reads above precede writes, per-wave private)
#pragma unroll
    for (int kk = 0; kk < 8; ++kk) hs[wv][kk][lane] = fmaxf(acc[kk], 0.f);

    // ---- layer3 (two o-halves) + max over this wave's 8 k ----
    float outmax[2];
#pragma unroll
    for (int p = 0; p < 2; ++p) {
        float w2col[64];
#pragma unroll
        for (int i = 0; i < 64; ++i) w2col[i] = W2[i * 128 + 64 * p + lane];
        const float b2v = b2[64 * p + lane];
        float acc3[8];
#pragma unroll
        for (int kk = 0; kk < 8; ++kk) acc3[kk] = b2v;
#pragma unroll
        for (int qd = 0; qd < 16; ++qd) {
#pragma unroll
            for (int kk = 0; kk < 8; ++kk) {
                float4 h4 = *(const float4*)&hs[wv][kk][4 * qd];
                acc3[kk] = fmaf(h4.x, w2col[4 * qd + 0], acc3[kk]);
                acc3[kk] = fmaf(h4.y, w2col[4 * qd + 1], acc3[kk]);
                acc3[kk] = fmaf(h4.z, w2col[4 * qd + 2], acc3[kk]);
                acc3[kk] = fmaf(h4.w, w2col[4 * qd + 3], acc3[kk]);
            }
        }
        float m = 0.f;  // relu floor: max(relu(x)) == max(0, max(x))
#pragma unroll
        for (int kk = 0; kk < 8; ++kk) m = fmaxf(m, acc3[kk]);
        outmax[p] = m;
    }
    part[wv][lane] = outmax[0];
    part[wv][64 + lane] = outmax[1];
    __syncthreads();
    if (t < 128) {
        float v = fmaxf(fmaxf(part[0][t], part[1][t]), fmaxf(part[2][t], part[3][t]));
        out_points[q * 128 + t] = v;
    }
}

extern "C" void kernel_launch(void* const* d_in, const int* in_sizes, int n_in,
                              void* d_out, int out_size, void* d_ws, size_t ws_size,
                              hipStream_t stream) {
    const float* xyz    = (const float*)d_in[0];
    const float* points = (const float*)d_in[1];
    const float* W0     = (const float*)d_in[2];
    const float* b0     = (const float*)d_in[3];
    const float* W1     = (const float*)d_in[4];
    const float* b1     = (const float*)d_in[5];
    const float* W2     = (const float*)d_in[6];
    const float* b2     = (const float*)d_in[7];
    float* out = (float*)d_out;
    float*  P1   = (float*)d_ws;                                        // B*N*64 f32 = 16 MB
    float4* xyz4 = (float4*)((char*)d_ws + (size_t)BB * NN * 64 * 4);   // B*N float4 = 1 MB

    // blocks 0..15: FPS (one per batch); blocks 16..271: P1+xyz4 (256 points each)
    hipLaunchKernelGGL(fused1_kernel, dim3(BB + (BB * NN) / 256), dim3(256), 0, stream,
                       xyz, points, W0, b0, P1, xyz4, out);
    hipLaunchKernelGGL(k3_kernel, dim3(BB * SS), dim3(256), 0, stream,
                       xyz4, P1, W0, W1, b1, W2, b2, out);
}